// Round 1
// baseline (211.922 us; speedup 1.0000x reference)
//
#include <hip/hip_runtime.h>
#include <cmath>

#define HH 256
#define WW 256
#define RAD 12
#define KLEN 25          // 2*RAD+1
#define NMAPS 512

// ---------------------------------------------------------------------------
// Kernel A: per-map fused gaussian blur + peak detect + argmax/count reduce
// One block per map (256 threads = 1 thread per column).
// Vertical conv first (register ring of padded rows, static indices),
// then horizontal conv from a symmetric-padded LDS row.
// ---------------------------------------------------------------------------
__global__ __launch_bounds__(256) void blur_peak_kernel(
    const float* __restrict__ in,
    float* __restrict__ bestval,
    int* __restrict__ bestidx,
    int* __restrict__ npk)
{
    __shared__ float vrow[WW + 2 * RAD];   // horizontally padded v row (280)
    __shared__ float gbuf[4][WW];          // ring of g rows for left/right tests
    __shared__ float red_v[256];
    __shared__ int   red_i[256];
    __shared__ int   red_c[256];

    const int j = threadIdx.x;
    const int m = blockIdx.x;
    const float* map = in + (size_t)m * HH * WW;

    // Gaussian coefficients (match reference: exp(-t^2/18)/sum, float32)
    float kf[KLEN];
    {
        float s = 0.f;
#pragma unroll
        for (int i = 0; i < KLEN; ++i) {
            float t = (float)(i - RAD);
            kf[i] = expf(-(t * t) / 18.0f);
            s += kf[i];
        }
#pragma unroll
        for (int i = 0; i < KLEN; ++i) kf[i] /= s;
    }

    // Register ring of vertically padded raw rows: ring[i] = padded[s-24+i]
    float ring[KLEN];
#pragma unroll
    for (int i = 0; i < KLEN; ++i) ring[i] = 0.f;

    // per-thread g history for this column: g0=g[o], gm1=g[o-1], gm2=g[o-2]
    float g0 = 0.f, gm1 = 0.f, gm2 = 0.f;

    float bval = -1.f;
    int   bidx = 0x7FFFFFFF;
    int   cnt  = 0;

    // padded row q = s corresponds to image row mirr(q - RAD), q in [0, 279]
    for (int s = 0; s <= 280; ++s) {
        // ---- phase A: load padded row s into ring ----
        float loaded = 0.f;
        if (s < HH + 2 * RAD) {
            int q = s - RAD;
            if (q < 0) q = -q - 1;                 // symmetric pad top
            if (q > HH - 1) q = 2 * HH - 1 - q;    // symmetric pad bottom
            loaded = map[q * WW + j];
        }
#pragma unroll
        for (int i = 0; i < KLEN - 1; ++i) ring[i] = ring[i + 1];
        ring[KLEN - 1] = loaded;

        // ---- phase B: vertical conv -> v row o, store padded into LDS ----
        const int o = s - 24;
        const bool doG = (o >= 0) && (o < HH);
        if (doG) {
            float v = 0.f;
#pragma unroll
            for (int d = 0; d < KLEN; ++d) v += kf[d] * ring[d];
            vrow[RAD + j] = v;
            if (j < RAD)      vrow[RAD - 1 - j] = v;              // left mirror
            if (j >= WW - RAD) vrow[RAD + 2 * WW - 1 - j] = v;    // right mirror
        }
        __syncthreads();   // vrow ready; also orders prev-step gbuf writes

        // ---- phase C: horizontal conv -> g[o]; evaluate peaks at row e=o-1 --
        if (doG) {
            float acc = 0.f;
#pragma unroll
            for (int d = 0; d < KLEN; ++d) acc += kf[d] * vrow[j + d];
            gbuf[o & 3][j] = acc;
            gm2 = gm1; gm1 = g0; g0 = acc;
        }

        const int e = s - 25;
        if (e >= 0) {
            float gE, up, dn;
            if (e < HH - 1) { gE = gm1; up = gm2; dn = g0;  }
            else            { gE = g0;  up = gm1; dn = 0.f; }   // last row: down pad = 0
            float lf = (j > 0)      ? gbuf[e & 3][j - 1] : 0.f;
            float rt = (j < WW - 1) ? gbuf[e & 3][j + 1] : 0.f;
            bool pk = (gE >= up) && (gE >= dn) && (gE >= lf) && (gE >= rt) && (gE > 0.01f);
            if (pk) {
                cnt++;
                float mv = ring[11];       // padded[s-13] = image row e (no mirror)
                int fi = e * WW + j;
                if (mv > bval) { bval = mv; bidx = fi; }   // '>' keeps first occurrence
            }
        }
        __syncthreads();   // vrow consumed; gbuf[o] visible for next step's eval
    }

    // ---- block reduction: (max val, min idx on tie), total count ----
    red_v[j] = bval; red_i[j] = bidx; red_c[j] = cnt;
    __syncthreads();
    for (int off = 128; off > 0; off >>= 1) {
        if (j < off) {
            float v2 = red_v[j + off]; int i2 = red_i[j + off];
            if (v2 > red_v[j] || (v2 == red_v[j] && i2 < red_i[j])) {
                red_v[j] = v2; red_i[j] = i2;
            }
            red_c[j] += red_c[j + off];
        }
        __syncthreads();
    }
    if (j == 0) {
        bestval[m] = red_v[0];
        bestidx[m] = red_i[0];
        npk[m]     = red_c[0];
    }
}

// ---------------------------------------------------------------------------
// Kernel B: per-map finalize — 5x5 window sums at winner + output logic
// ---------------------------------------------------------------------------
__global__ __launch_bounds__(256) void finalize_kernel(
    const float* __restrict__ in,
    const float* __restrict__ bestval,
    const int* __restrict__ bestidx,
    const int* __restrict__ npk,
    float* __restrict__ out)
{
    int t = blockIdx.x * blockDim.x + threadIdx.x;
    if (t >= NMAPS) return;

    int   c  = npk[t];
    float sc = bestval[t];
    bool valid = (c == 1) || ((c > 1) && (sc >= 0.8f));

    float kx = -999.999f, ky = -999.999f, conf = 0.f;
    if (valid) {
        int fi = bestidx[t];
        int pr = fi / WW, pc = fi % WW;
        const float* map = in + (size_t)t * HH * WW;
        float S = 0.f, SX = 0.f, SY = 0.f;
#pragma unroll
        for (int dr = -2; dr <= 2; ++dr) {
            int r = pr + dr;
            if (r < 0 || r >= HH) continue;
#pragma unroll
            for (int dc = -2; dc <= 2; ++dc) {
                int cc = pc + dc;
                if (cc < 0 || cc >= WW) continue;
                float mv = map[r * WW + cc];
                S  += mv;
                SX += mv * (float)cc;
                SY += mv * (float)r;
            }
        }
        float x = (S == 0.f) ? (float)pc : (SX / S);
        float y = (S == 0.f) ? (float)pr : (SY / S);
        kx = x + 0.4395f;
        ky = y + 0.4395f;
        conf = 1.f;
    }
    out[t * 3 + 0] = kx;
    out[t * 3 + 1] = ky;
    out[t * 3 + 2] = conf;
}

extern "C" void kernel_launch(void* const* d_in, const int* in_sizes, int n_in,
                              void* d_out, int out_size, void* d_ws, size_t ws_size,
                              hipStream_t stream) {
    const float* in = (const float*)d_in[0];
    float* out = (float*)d_out;

    // workspace layout: 512 floats bestval | 512 ints bestidx | 512 ints npk
    float* bestval = (float*)d_ws;
    int*   bestidx = (int*)((char*)d_ws + NMAPS * sizeof(float));
    int*   npk     = (int*)((char*)d_ws + 2 * NMAPS * sizeof(float));

    blur_peak_kernel<<<NMAPS, 256, 0, stream>>>(in, bestval, bestidx, npk);
    finalize_kernel<<<(NMAPS + 255) / 256, 256, 0, stream>>>(in, bestval, bestidx, npk, out);
}

// Round 2
// 108.432 us; speedup vs baseline: 1.9544x; 1.9544x over previous
//
#include <hip/hip_runtime.h>
#include <cmath>

#define HH 256
#define WW 256
#define RAD 12
#define KLEN 25          // 2*RAD+1
#define NMAPS 512
#define ESTRIP 32        // eval rows per strip
#define NSTRIP (HH / ESTRIP)   // 8
#define NITER (ESTRIP + 2)     // 34: o = e0-1 .. e0+32

// ---------------------------------------------------------------------------
// Kernel A: per-strip fused gaussian blur + peak detect + argmax/count reduce
// One block per (map, strip). 256 threads = 1 thread per column.
// Vertical conv from a 25-deep register ring (fully unrolled -> renamed),
// horizontal conv from a symmetric-padded, double-buffered LDS row.
// ---------------------------------------------------------------------------
__global__ __launch_bounds__(256) void blur_peak_strip(
    const float* __restrict__ in,
    float* __restrict__ sval,
    int* __restrict__ sidx,
    int* __restrict__ scnt)
{
    __shared__ float vrow[2][WW + 2 * RAD];  // double-buffered padded v row
    __shared__ float gbuf[4][WW];            // ring of g rows for left/right tests
    __shared__ float rv[4];
    __shared__ int   ri[4];
    __shared__ int   rc[4];

    const int j     = threadIdx.x;
    const int blk   = blockIdx.x;
    const int m     = blk >> 3;        // map
    const int strip = blk & 7;         // strip within map
    const float* map = in + (size_t)m * HH * WW;

    const int e0 = strip * ESTRIP;     // first eval row
    const int o0 = e0 - 1;             // first g row computed

    // Gaussian coefficients, symmetric half (13 regs). Same float32 math as ref.
    float kf[RAD + 1];
    {
        float s = 0.f;
#pragma unroll
        for (int i = 0; i <= RAD; ++i) {
            float t = (float)(i - RAD);
            kf[i] = expf(-(t * t) / 18.0f);
            s += (i < RAD) ? 2.f * kf[i] : kf[i];
        }
#pragma unroll
        for (int i = 0; i <= RAD; ++i) kf[i] /= s;
    }

    // Register ring: after the append in iter t (o = o0+t), ring[i] = padded[o+i],
    // where padded[q] = raw[mirr(q-12)].
    float ring[KLEN];
#pragma unroll
    for (int i = 1; i < KLEN; ++i) {
        int q = o0 + i - 1;
        int r = q - RAD;
        if (r < 0) r = -r - 1;
        if (r > HH - 1) r = 2 * HH - 1 - r;
        ring[i] = map[r * WW + j];
    }
    ring[0] = 0.f;

    float g0 = 0.f, gm1 = 0.f, gm2 = 0.f;
    float bval = -1.f;
    int   bidx = 0x7FFFFFFF;
    int   cnt  = 0;

#pragma unroll
    for (int t = 0; t < NITER; ++t) {
        const int o = o0 + t;          // g row computed this iter

        // ---- append padded[o+24] ----
        {
            int r = o + 12;            // (o+24) - RAD
            if (r > HH - 1) r = 2 * HH - 1 - r;   // bottom mirror (top impossible here)
            float nv = map[r * WW + j];
#pragma unroll
            for (int i = 0; i < KLEN - 1; ++i) ring[i] = ring[i + 1];
            ring[KLEN - 1] = nv;
        }

        // ---- vertical conv (symmetric taps) ----
        float v = kf[RAD] * ring[RAD];
#pragma unroll
        for (int d = 0; d < RAD; ++d) v += kf[d] * (ring[d] + ring[2 * RAD - d]);

        float* vr = vrow[t & 1];
        vr[RAD + j] = v;
        if (j < RAD)        vr[RAD - 1 - j] = v;             // left mirror
        if (j >= WW - RAD)  vr[RAD + 2 * WW - 1 - j] = v;    // right mirror
        __syncthreads();

        // ---- horizontal conv ----
        float acc = kf[RAD] * vr[j + RAD];
#pragma unroll
        for (int d = 0; d < RAD; ++d) acc += kf[d] * (vr[j + d] + vr[j + 2 * RAD - d]);
        gbuf[o & 3][j] = acc;
        gm2 = gm1; gm1 = g0; g0 = acc;

        // ---- peak eval at e = o-1 (valid for t >= 2) ----
        if (t >= 2) {
            const int e = o - 1;
            float gE = gm1;
            float up = (e == 0)      ? 0.f : gm2;
            float dn = (e == HH - 1) ? 0.f : g0;
            float lf = (j > 0)      ? gbuf[e & 3][j - 1] : 0.f;
            float rt = (j < WW - 1) ? gbuf[e & 3][j + 1] : 0.f;
            bool pk = (gE >= up) && (gE >= dn) && (gE >= lf) && (gE >= rt) && (gE > 0.01f);
            if (pk) {
                cnt++;
                float mv = ring[11];   // padded[o+11] = raw row e (always in range)
                int fi = e * WW + j;
                if (mv > bval) { bval = mv; bidx = fi; }  // '>' keeps first occurrence
            }
        }
    }

    // ---- wave butterfly reduction: (max val, min idx on tie), sum count ----
#pragma unroll
    for (int off = 32; off > 0; off >>= 1) {
        float v2 = __shfl_xor(bval, off);
        int   i2 = __shfl_xor(bidx, off);
        int   c2 = __shfl_xor(cnt,  off);
        if (v2 > bval || (v2 == bval && i2 < bidx)) { bval = v2; bidx = i2; }
        cnt += c2;
    }
    const int w = j >> 6;
    if ((j & 63) == 0) { rv[w] = bval; ri[w] = bidx; rc[w] = cnt; }
    __syncthreads();
    if (j == 0) {
        float BV = rv[0]; int BI = ri[0]; int C = rc[0];
#pragma unroll
        for (int ww2 = 1; ww2 < 4; ++ww2) {
            if (rv[ww2] > BV || (rv[ww2] == BV && ri[ww2] < BI)) { BV = rv[ww2]; BI = ri[ww2]; }
            C += rc[ww2];
        }
        sval[blk] = BV; sidx[blk] = BI; scnt[blk] = C;
    }
}

// ---------------------------------------------------------------------------
// Kernel B: per-map combine strips + 5x5 window sums at winner + output logic
// ---------------------------------------------------------------------------
__global__ __launch_bounds__(256) void finalize_kernel(
    const float* __restrict__ in,
    const float* __restrict__ sval,
    const int* __restrict__ sidx,
    const int* __restrict__ scnt,
    float* __restrict__ out)
{
    int t = blockIdx.x * blockDim.x + threadIdx.x;
    if (t >= NMAPS) return;

    float BV = -1.f; int BI = 0x7FFFFFFF; int C = 0;
#pragma unroll
    for (int s2 = 0; s2 < NSTRIP; ++s2) {
        int k = t * NSTRIP + s2;
        float v = sval[k]; int i = sidx[k];
        if (v > BV || (v == BV && i < BI)) { BV = v; BI = i; }
        C += scnt[k];
    }

    bool valid = (C == 1) || ((C > 1) && (BV >= 0.8f));

    float kx = -999.999f, ky = -999.999f, conf = 0.f;
    if (valid) {
        int pr = BI / WW, pc = BI % WW;
        const float* map = in + (size_t)t * HH * WW;
        float S = 0.f, SX = 0.f, SY = 0.f;
#pragma unroll
        for (int dr = -2; dr <= 2; ++dr) {
            int r = pr + dr;
            if (r < 0 || r >= HH) continue;
#pragma unroll
            for (int dc = -2; dc <= 2; ++dc) {
                int cc = pc + dc;
                if (cc < 0 || cc >= WW) continue;
                float mv = map[r * WW + cc];
                S  += mv;
                SX += mv * (float)cc;
                SY += mv * (float)r;
            }
        }
        float x = (S == 0.f) ? (float)pc : (SX / S);
        float y = (S == 0.f) ? (float)pr : (SY / S);
        kx = x + 0.4395f;
        ky = y + 0.4395f;
        conf = 1.f;
    }
    out[t * 3 + 0] = kx;
    out[t * 3 + 1] = ky;
    out[t * 3 + 2] = conf;
}

extern "C" void kernel_launch(void* const* d_in, const int* in_sizes, int n_in,
                              void* d_out, int out_size, void* d_ws, size_t ws_size,
                              hipStream_t stream) {
    const float* in = (const float*)d_in[0];
    float* out = (float*)d_out;

    const int nblk = NMAPS * NSTRIP;   // 4096
    // workspace: nblk floats sval | nblk ints sidx | nblk ints scnt  (48 KB)
    float* sval = (float*)d_ws;
    int*   sidx = (int*)((char*)d_ws + (size_t)nblk * 4);
    int*   scnt = (int*)((char*)d_ws + (size_t)nblk * 8);

    blur_peak_strip<<<nblk, 256, 0, stream>>>(in, sval, sidx, scnt);
    finalize_kernel<<<(NMAPS + 255) / 256, 256, 0, stream>>>(in, sval, sidx, scnt, out);
}